// Round 1
// baseline (229.532 us; speedup 1.0000x reference)
//
#include <hip/hip_runtime.h>

typedef short short8 __attribute__((ext_vector_type(8)));
typedef float f32x4 __attribute__((ext_vector_type(4)));
typedef unsigned short u16;

__device__ __forceinline__ u16 f2bf(float f) {
  unsigned int u = __builtin_bit_cast(unsigned int, f);
  u = (u + 0x7FFFu + ((u >> 16) & 1u)) >> 16;
  return (u16)u;
}

__device__ __forceinline__ short8 cvt8(float4 a, float4 b) {
  short8 v;
  v[0] = (short)f2bf(a.x); v[1] = (short)f2bf(a.y);
  v[2] = (short)f2bf(a.z); v[3] = (short)f2bf(a.w);
  v[4] = (short)f2bf(b.x); v[5] = (short)f2bf(b.y);
  v[6] = (short)f2bf(b.z); v[7] = (short)f2bf(b.w);
  return v;
}

__device__ __forceinline__ float sigmoidf_fast(float x) {
  return __builtin_amdgcn_rcpf(1.0f + __expf(-x));
}
__device__ __forceinline__ float tanhf_fast(float x) {
  return 1.0f - 2.0f * __builtin_amdgcn_rcpf(1.0f + __expf(2.0f * x));
}

// ---------------------------------------------------------------------------
// Scan kernel: 4 directions x 64 blocks; each block owns 48 sequences.
// Per step: gates[48x192] = [x_t | h | 0][48x256] @ B[256x192] (bf16 MFMA),
// then register-resident LSTM cell update (wave w owns hd-tile w, all 4 gates).
// ---------------------------------------------------------------------------
__global__ __launch_bounds__(192, 1)
void bilstm_scan_kernel(
    const float* __restrict__ x,
    const float* __restrict__ wih_vf, const float* __restrict__ whh_vf,
    const float* __restrict__ bih_vf, const float* __restrict__ bhh_vf,
    const float* __restrict__ wih_vb, const float* __restrict__ whh_vb,
    const float* __restrict__ bih_vb, const float* __restrict__ bhh_vb,
    const float* __restrict__ wih_hf, const float* __restrict__ whh_hf,
    const float* __restrict__ bih_hf, const float* __restrict__ bhh_hf,
    const float* __restrict__ wih_hb, const float* __restrict__ whh_hb,
    const float* __restrict__ bih_hb, const float* __restrict__ bhh_hb,
    u16* __restrict__ comb)
{
  __shared__ u16 lds[61440];           // 120 KB
  u16* Alds = lds;                     // [48][256] bf16, XOR-swizzled
  u16* Blds = lds + 12288;             // [192][256] bf16, XOR-swizzled

  const int tid  = threadIdx.x;
  const int lane = tid & 63;
  const int wv   = tid >> 6;           // wave 0..2 -> hd-tile
  const int cl   = lane & 15;
  const int kg   = lane >> 4;          // 0..3
  const int dir  = blockIdx.x >> 6;    // 0 v_f, 1 v_b, 2 h_f, 3 h_b
  const int blk  = blockIdx.x & 63;
  const int base = blk * 48;
  const bool vert = dir < 2;
  const bool bwd  = (dir & 1) != 0;

  const float *wih, *whh, *bih, *bhh;
  if      (dir == 0) { wih = wih_vf; whh = whh_vf; bih = bih_vf; bhh = bhh_vf; }
  else if (dir == 1) { wih = wih_vb; whh = whh_vb; bih = bih_vb; bhh = bhh_vb; }
  else if (dir == 2) { wih = wih_hf; whh = whh_hf; bih = bih_hf; bhh = bhh_hf; }
  else               { wih = wih_hb; whh = whh_hb; bih = bih_hb; bhh = bhh_hb; }

  // ---- stage B = [w_ih (192) | w_hh (48) | zeros (16)] per column, bf16
  for (int i = 0; i < 32; ++i) {
    int ch = tid + 192 * i;            // 0..6143
    int n  = ch >> 5;
    int k0 = (ch & 31) << 3;
    short8 v = {};
    if (k0 < 192) {
      const float4* s0 = (const float4*)(wih + n * 192 + k0);
      v = cvt8(s0[0], s0[1]);
    } else if (k0 < 240) {
      const float4* s0 = (const float4*)(whh + n * 48 + (k0 - 192));
      v = cvt8(s0[0], s0[1]);
    }
    *(short8*)(&Blds[(n * 256 + k0) ^ ((n & 7) << 3)]) = v;
  }
  // ---- zero h + pad region of A (k in [192,256)), so t=0 sees h=0
  for (int i = 0; i < 2; ++i) {
    int ch = tid + 192 * i;            // 0..383
    int s  = ch >> 3;
    int k0 = 192 + ((ch & 7) << 3);
    short8 z = {};
    *(short8*)(&Alds[(s * 256 + k0) ^ ((s & 7) << 3)]) = z;
  }
  // ---- per-lane bias (i,f,g,o for this lane's hd)
  float bias[4];
  #pragma unroll
  for (int g = 0; g < 4; ++g) {
    int col = g * 48 + wv * 16 + cl;
    bias[g] = bih[col] + bhh[col];
  }

  auto stage_x = [&](int tt) {
    int tp = bwd ? 47 - tt : tt;
    #pragma unroll
    for (int i = 0; i < 6; ++i) {
      int ch = tid + 192 * i;          // 0..1151
      int s  = ch / 24;
      int k0 = (ch % 24) << 3;
      int sq = base + s;
      int bb = sq / 48;
      int rc = sq - bb * 48;
      size_t poff = vert ? (size_t)((bb * 48 + tp) * 48 + rc) * 192
                         : (size_t)((bb * 48 + rc) * 48 + tp) * 192;
      const float4* sp = (const float4*)(x + poff + k0);
      float4 u0 = sp[0], u1 = sp[1];
      *(short8*)(&Alds[(s * 256 + k0) ^ ((s & 7) << 3)]) = cvt8(u0, u1);
    }
  };
  stage_x(0);

  float c[12];
  #pragma unroll
  for (int i = 0; i < 12; ++i) c[i] = 0.0f;

  const int hd = wv * 16 + cl;

  for (int t = 0; t < 48; ++t) {
    __syncthreads();

    // ---- GEMM: gates = A[48x256] * B[256x192]
    f32x4 acc[3][4] = {};
    #pragma unroll
    for (int kk = 0; kk < 8; ++kk) {
      int krow = kk * 32 + kg * 8;
      short8 af[3], bf[4];
      #pragma unroll
      for (int mi = 0; mi < 3; ++mi) {
        int row = mi * 16 + cl;
        af[mi] = *(const short8*)(&Alds[(row * 256 + krow) ^ ((row & 7) << 3)]);
      }
      #pragma unroll
      for (int g = 0; g < 4; ++g) {
        int col = g * 48 + wv * 16 + cl;
        bf[g] = *(const short8*)(&Blds[(col * 256 + krow) ^ ((col & 7) << 3)]);
      }
      #pragma unroll
      for (int mi = 0; mi < 3; ++mi)
        #pragma unroll
        for (int g = 0; g < 4; ++g)
          acc[mi][g] = __builtin_amdgcn_mfma_f32_16x16x32_bf16(
              af[mi], bf[g], acc[mi][g], 0, 0, 0);
    }
    __syncthreads();

    int tp = bwd ? 47 - t : t;
    if (t < 47) stage_x(t + 1);   // issue global loads early; hides under epilogue

    // ---- epilogue: lane holds i,f,g,o for its (seq, hd) positions
    #pragma unroll
    for (int mi = 0; mi < 3; ++mi) {
      #pragma unroll
      for (int r = 0; r < 4; ++r) {
        int s = mi * 16 + kg * 4 + r;
        float xi = acc[mi][0][r] + bias[0];
        float xf = acc[mi][1][r] + bias[1];
        float xg = acc[mi][2][r] + bias[2];
        float xo = acc[mi][3][r] + bias[3];
        float ii = sigmoidf_fast(xi);
        float ff = sigmoidf_fast(xf);
        float gg = tanhf_fast(xg);
        float oo = sigmoidf_fast(xo);
        float cc = ff * c[mi * 4 + r] + ii * gg;
        c[mi * 4 + r] = cc;
        float hh = oo * tanhf_fast(cc);
        u16 hb = f2bf(hh);
        // h -> A tile for next step (k = 192+hd), swizzled
        Alds[(s * 256 + 192 + hd) ^ ((s & 7) << 3)] = hb;
        // h -> combined buffer at this timestep's pixel
        int sq = base + s;
        int bb = sq / 48;
        int rc = sq - bb * 48;
        int p = vert ? (bb * 48 + tp) * 48 + rc : (bb * 48 + rc) * 48 + tp;
        comb[(size_t)p * 192 + dir * 48 + hd] = hb;
      }
    }
  }
}

// ---------------------------------------------------------------------------
// Projection: out[p][c] = sum_k comb[p][k] * proj_w[c][k] + proj_b[c]
// ---------------------------------------------------------------------------
__global__ __launch_bounds__(256, 1)
void proj_kernel(const u16* __restrict__ comb,
                 const float* __restrict__ pw,
                 const float* __restrict__ pb,
                 float* __restrict__ out)
{
  __shared__ u16 lds[49152];           // 96 KB
  u16* Alds = lds;                     // [64][192] bf16, swizzled
  u16* Blds = lds + 12288;             // [192][192] bf16, swizzled

  const int tid = threadIdx.x;
  const int lane = tid & 63;
  const int wv = tid >> 6;             // 0..3 -> col block of 48
  const int cl = lane & 15;
  const int kg = lane >> 4;
  const size_t p0 = (size_t)blockIdx.x * 64;

  for (int i = 0; i < 18; ++i) {
    int ch = tid + 256 * i;            // 0..4607
    int n  = ch / 24;
    int k0 = (ch % 24) << 3;
    const float4* s0 = (const float4*)(pw + n * 192 + k0);
    *(short8*)(&Blds[(n * 192 + k0) ^ ((n & 7) << 3)]) = cvt8(s0[0], s0[1]);
  }
  for (int i = 0; i < 6; ++i) {
    int ch = tid + 256 * i;            // 0..1535
    int s  = ch / 24;
    int k0 = (ch % 24) << 3;
    short8 v = *(const short8*)(comb + (p0 + s) * 192 + k0);
    *(short8*)(&Alds[(s * 192 + k0) ^ ((s & 7) << 3)]) = v;
  }
  float pbr[3];
  #pragma unroll
  for (int ni = 0; ni < 3; ++ni) pbr[ni] = pb[wv * 48 + ni * 16 + cl];

  __syncthreads();

  f32x4 acc[4][3] = {};
  #pragma unroll
  for (int kk = 0; kk < 6; ++kk) {
    int krow = kk * 32 + kg * 8;
    short8 af[4], bf[3];
    #pragma unroll
    for (int mi = 0; mi < 4; ++mi) {
      int row = mi * 16 + cl;
      af[mi] = *(const short8*)(&Alds[(row * 192 + krow) ^ ((row & 7) << 3)]);
    }
    #pragma unroll
    for (int ni = 0; ni < 3; ++ni) {
      int col = wv * 48 + ni * 16 + cl;
      bf[ni] = *(const short8*)(&Blds[(col * 192 + krow) ^ ((col & 7) << 3)]);
    }
    #pragma unroll
    for (int mi = 0; mi < 4; ++mi)
      #pragma unroll
      for (int ni = 0; ni < 3; ++ni)
        acc[mi][ni] = __builtin_amdgcn_mfma_f32_16x16x32_bf16(
            af[mi], bf[ni], acc[mi][ni], 0, 0, 0);
  }

  #pragma unroll
  for (int mi = 0; mi < 4; ++mi)
    #pragma unroll
    for (int ni = 0; ni < 3; ++ni)
      #pragma unroll
      for (int r = 0; r < 4; ++r) {
        size_t o = (p0 + mi * 16 + kg * 4 + r) * 192 + wv * 48 + ni * 16 + cl;
        out[o] = acc[mi][ni][r] + pbr[ni];
      }
}

extern "C" void kernel_launch(void* const* d_in, const int* in_sizes, int n_in,
                              void* d_out, int out_size, void* d_ws, size_t ws_size,
                              hipStream_t stream) {
  const float* x = (const float*)d_in[0];
  u16* comb = (u16*)d_ws;   // [147456][192] bf16 = 54 MB

  bilstm_scan_kernel<<<256, 192, 0, stream>>>(
      x,
      (const float*)d_in[1],  (const float*)d_in[2],  (const float*)d_in[3],  (const float*)d_in[4],
      (const float*)d_in[5],  (const float*)d_in[6],  (const float*)d_in[7],  (const float*)d_in[8],
      (const float*)d_in[9],  (const float*)d_in[10], (const float*)d_in[11], (const float*)d_in[12],
      (const float*)d_in[13], (const float*)d_in[14], (const float*)d_in[15], (const float*)d_in[16],
      comb);

  proj_kernel<<<2304, 256, 0, stream>>>(
      comb, (const float*)d_in[17], (const float*)d_in[18], (float*)d_out);
}